// Round 1
// baseline (302.733 us; speedup 1.0000x reference)
//
#include <hip/hip_runtime.h>
#include <cstdint>

#define DEVI static __device__ __forceinline__

typedef __attribute__((ext_vector_type(8))) short bf16x8;
typedef __attribute__((ext_vector_type(4))) float f32x4;
typedef __attribute__((ext_vector_type(8))) unsigned short ush8;

DEVI unsigned short f2bf(float f) {
    unsigned u = __float_as_uint(f);
    u += 0x7fff + ((u >> 16) & 1);
    return (unsigned short)(u >> 16);
}
DEVI float bf2f(unsigned short h) { return __uint_as_float(((unsigned)h) << 16); }

DEVI void gload16(const void* g, void* l) {
    __builtin_amdgcn_global_load_lds((const __attribute__((address_space(1))) void*)g,
                                     (__attribute__((address_space(3))) void*)l, 16, 0, 0);
}

// ---------------- weight conversion: fp32 -> bf16 ----------------
// dst layout (ushort units): [0,110592) Wqkv(576x192) | [110592,147456) Wp |
// [147456,294912) Wf1(768x192) | [294912,442368) Wf2(192x768)
__global__ __launch_bounds__(256) void k_cvt(const float* __restrict__ Wq, const float* __restrict__ Wkv,
                                             const float* __restrict__ Wp, const float* __restrict__ Wf1,
                                             const float* __restrict__ Wf2, unsigned short* __restrict__ dst) {
    int t = blockIdx.x * 256 + threadIdx.x;
    if (t < 110592) {
        float v = (t < 36864) ? Wq[t] * 0.17677669529663687f : Wkv[t - 36864];
        dst[t] = f2bf(v);
    } else if (t < 147456) dst[t] = f2bf(Wp[t - 110592]);
    else if (t < 294912) dst[t] = f2bf(Wf1[t - 147456]);
    else if (t < 442368) dst[t] = f2bf(Wf2[t - 294912]);
}

// ---------------- dense rel-pos bias table: [6][128][128] f32 ----------------
__global__ __launch_bounds__(256) void k_bias(const float* __restrict__ rpb, float* __restrict__ bias) {
    int t = blockIdx.x * 256 + threadIdx.x;  // 6*16384
    if (t >= 98304) return;
    int h = t >> 14, ij = t & 16383, i = ij >> 7, j = ij & 127;
    int tdi = i >> 6, thi = (i >> 3) & 7, twi = i & 7;
    int tdj = j >> 6, thj = (j >> 3) & 7, twj = j & 7;
    int idx = ((tdi - tdj + 1) * 15 + (thi - thj + 7)) * 15 + (twi - twj + 7);
    bias[t] = rpb[idx * 6 + h];
}

// ---------------- LayerNorm (optionally fused with roll+window gather) ----------------
// GATHER=1: output row t is window-order token; source is original layout w/ shift roll.
template <int GATHER>
__global__ __launch_bounds__(256) void k_ln(const float* __restrict__ x, const float* __restrict__ g,
                                            const float* __restrict__ b, unsigned short* __restrict__ outp) {
    int wid = threadIdx.x >> 6, lane = threadIdx.x & 63;
    int t = blockIdx.x * 4 + wid;
    long src;
    if (GATHER) {
        int w = t >> 7, tt = t & 127;
        int bb = w >> 8, rem = w & 255;
        int dw = rem >> 6, hw = (rem >> 3) & 7, ww = rem & 7;
        int td = tt >> 6, th = (tt >> 3) & 7, tw = tt & 7;
        int d = (dw * 2 + td + 1) & 7;
        int hh = (hw * 8 + th + 4) & 63;
        int wo = (ww * 8 + tw + 4) & 63;
        src = (long)((bb * 8 + d) * 64 + hh) * 64 + wo;
    } else src = t;
    const float* xp = x + src * 192;
    float v0 = xp[lane], v1 = xp[lane + 64], v2 = xp[lane + 128];
    float s = v0 + v1 + v2, ss = v0 * v0 + v1 * v1 + v2 * v2;
    #pragma unroll
    for (int m = 32; m; m >>= 1) { s += __shfl_xor(s, m); ss += __shfl_xor(ss, m); }
    float mu = s * (1.f / 192.f);
    float var = ss * (1.f / 192.f) - mu * mu;
    float inv = rsqrtf(var + 1e-5f);
    unsigned short* op = outp + (long)t * 192;
    op[lane]       = f2bf((v0 - mu) * inv * g[lane]       + b[lane]);
    op[lane + 64]  = f2bf((v1 - mu) * inv * g[lane + 64]  + b[lane + 64]);
    op[lane + 128] = f2bf((v2 - mu) * inv * g[lane + 128] + b[lane + 128]);
}

// ---------------- generic bf16 MFMA GEMM: C[M,N] = A[M,K] @ B[N,K]^T ----------------
// 128x64 tile, 4 waves (2x2), wave tile 64x32 (4x2 frags of 16x16), BK=32.
// EPI: 0=QKV scatter, 1=proj + window-reverse + residual (f32), 2=bias+GELU (bf16), 3=bias+residual (f32)
#define BM 128
#define BN 64

template <int EPI>
__global__ __launch_bounds__(256, 2) void k_gemm(const unsigned short* __restrict__ A,
                                                 const unsigned short* __restrict__ Bw, int K,
                                                 const float* __restrict__ bias,
                                                 const float* __restrict__ addsrc,
                                                 float* __restrict__ outF,
                                                 unsigned short* __restrict__ outU, int row0) {
    __shared__ __align__(16) unsigned short As[BM * 32];
    __shared__ __align__(16) unsigned short Bs[BN * 32];
    int tid = threadIdx.x;
    int wid = tid >> 6, lane = tid & 63;
    int g = lane >> 4, li = lane & 15;
    int m0 = blockIdx.x * BM, n0 = blockIdx.y * BN;
    int wm = wid >> 1, wn = wid & 1;

    f32x4 acc[4][2];
    #pragma unroll
    for (int i = 0; i < 4; i++)
        #pragma unroll
        for (int j = 0; j < 2; j++) acc[i][j] = (f32x4){0.f, 0.f, 0.f, 0.f};

    const unsigned short* ga0 = A + (long)(m0 + (tid >> 2)) * K + (tid & 3) * 8;
    const unsigned short* ga1 = A + (long)(m0 + 64 + (tid >> 2)) * K + (tid & 3) * 8;
    const unsigned short* gb  = Bw + (long)(n0 + (tid >> 2)) * K + (tid & 3) * 8;

    for (int kt = 0; kt < K; kt += 32) {
        gload16(ga0 + kt, As + tid * 8);
        gload16(ga1 + kt, As + (256 + tid) * 8);
        gload16(gb + kt, Bs + tid * 8);
        __syncthreads();
        bf16x8 af[4], bfr[2];
        #pragma unroll
        for (int i = 0; i < 4; i++)
            af[i] = *(const bf16x8*)&As[(wm * 64 + i * 16 + li) * 32 + g * 8];
        #pragma unroll
        for (int j = 0; j < 2; j++)
            bfr[j] = *(const bf16x8*)&Bs[(wn * 32 + j * 16 + li) * 32 + g * 8];
        #pragma unroll
        for (int i = 0; i < 4; i++)
            #pragma unroll
            for (int j = 0; j < 2; j++)
                acc[i][j] = __builtin_amdgcn_mfma_f32_16x16x32_bf16(af[i], bfr[j], acc[i][j], 0, 0, 0);
        __syncthreads();
    }

    #pragma unroll
    for (int i = 0; i < 4; i++) {
        int rowb = m0 + wm * 64 + i * 16 + g * 4;
        #pragma unroll
        for (int j = 0; j < 2; j++) {
            int col = n0 + wn * 32 + j * 16 + li;
            #pragma unroll
            for (int r = 0; r < 4; r++) {
                float v = acc[i][j][r];
                int rr = rowb + r;
                if (EPI == 0) {
                    int sec = col / 192;
                    int cc = col - sec * 192;
                    int h = cc >> 5, d = cc & 31;
                    int w = rr >> 7, n = rr & 127;
                    outU[(((long)sec * 3072 + w * 6 + h) * 128 + n) * 32 + d] = f2bf(v);
                } else if (EPI == 1) {
                    int w = rr >> 7, tt = rr & 127;
                    int bb = w >> 8, rem = w & 255;
                    int dw = rem >> 6, hw = (rem >> 3) & 7, ww = rem & 7;
                    int td = tt >> 6, th = (tt >> 3) & 7, tw = tt & 7;
                    int d = (dw * 2 + td + 1) & 7;
                    int hh = (hw * 8 + th + 4) & 63;
                    int wo = (ww * 8 + tw + 4) & 63;
                    long src = ((long)((bb * 8 + d) * 64 + hh) * 64 + wo) * 192 + col;
                    outF[src] = addsrc[src] + v + bias[col];
                } else if (EPI == 2) {
                    float tt = v + bias[col];
                    float ge = 0.5f * tt * (1.f + erff(tt * 0.70710678118f));
                    outU[(long)rr * 768 + col] = f2bf(ge);
                } else {
                    long idx = (long)(row0 + rr) * 192 + col;
                    outF[idx] = addsrc[idx] + v + bias[col];
                }
            }
        }
    }
}

// ---------------- attention: one block per (window, head) ----------------
DEVI int region(int tok, int dw, int hw, int ww) {
    int td = tok >> 6, th = (tok >> 3) & 7, tw = tok & 7;
    int rd = (dw == 3) ? (1 + td) : 0;
    int rh = (hw == 7) ? ((th < 4) ? 1 : 2) : 0;
    int rw = (ww == 7) ? ((tw < 4) ? 1 : 2) : 0;
    return rd * 9 + rh * 3 + rw;
}

__global__ __launch_bounds__(256, 2) void k_attn(const unsigned short* __restrict__ qkv,
                                                 const float* __restrict__ biasT,
                                                 unsigned short* __restrict__ attnout) {
    __shared__ __align__(16) unsigned short q_s[128 * 40];
    __shared__ __align__(16) unsigned short k_s[128 * 40];
    __shared__ __align__(16) unsigned short vt_s[32 * 136];
    __shared__ __align__(16) unsigned short p_s[128 * 136];
    int w = blockIdx.x, h = blockIdx.y;
    int tid = threadIdx.x, wid = tid >> 6, lane = tid & 63, g = lane >> 4, li = lane & 15;
    int rem = w & 255;
    int dw = rem >> 6, hw = (rem >> 3) & 7, ww = rem & 7;

    const unsigned short* qg = qkv + (long)(w * 6 + h) * 4096;
    const unsigned short* kg = qg + (long)3072 * 4096;
    const unsigned short* vg = qg + (long)6144 * 4096;

    #pragma unroll
    for (int c = tid; c < 512; c += 256) {
        int row = c >> 2, sub = c & 3;
        *(uint4*)&q_s[row * 40 + sub * 8] = *(const uint4*)&qg[row * 32 + sub * 8];
        *(uint4*)&k_s[row * 40 + sub * 8] = *(const uint4*)&kg[row * 32 + sub * 8];
    }
    {
        int key = tid >> 1, d0 = (tid & 1) * 16;
        const unsigned short* vp = vg + key * 32 + d0;
        ush8 va = *(const ush8*)vp, vb = *(const ush8*)(vp + 8);
        #pragma unroll
        for (int dd = 0; dd < 8; dd++) vt_s[(d0 + dd) * 136 + key] = va[dd];
        #pragma unroll
        for (int dd = 0; dd < 8; dd++) vt_s[(d0 + 8 + dd) * 136 + key] = vb[dd];
    }
    __syncthreads();

    // QK^T: wave wid owns query rows wid*32 .. wid*32+31
    f32x4 s[2][8];
    #pragma unroll
    for (int i = 0; i < 2; i++)
        #pragma unroll
        for (int j = 0; j < 8; j++) s[i][j] = (f32x4){0.f, 0.f, 0.f, 0.f};
    bf16x8 qa[2];
    #pragma unroll
    for (int fm = 0; fm < 2; fm++)
        qa[fm] = *(const bf16x8*)&q_s[(wid * 32 + fm * 16 + li) * 40 + g * 8];
    #pragma unroll
    for (int fn = 0; fn < 8; fn++) {
        bf16x8 kb = *(const bf16x8*)&k_s[(fn * 16 + li) * 40 + g * 8];
        s[0][fn] = __builtin_amdgcn_mfma_f32_16x16x32_bf16(qa[0], kb, s[0][fn], 0, 0, 0);
        s[1][fn] = __builtin_amdgcn_mfma_f32_16x16x32_bf16(qa[1], kb, s[1][fn], 0, 0, 0);
    }

    // bias + mask + softmax + write P (bf16) to LDS
    const float* bt = biasT + h * 16384;
    int boundary = (dw == 3) | (hw == 7) | (ww == 7);
    #pragma unroll
    for (int fm = 0; fm < 2; fm++) {
        #pragma unroll
        for (int r = 0; r < 4; r++) {
            int i = wid * 32 + fm * 16 + g * 4 + r;
            int regi = region(i, dw, hw, ww);
            float vals[8];
            float mx = -1e30f;
            #pragma unroll
            for (int fn = 0; fn < 8; fn++) {
                int j = fn * 16 + li;
                float v = s[fm][fn][r] + bt[i * 128 + j];
                if (boundary && region(j, dw, hw, ww) != regi) v -= 100.f;
                vals[fn] = v;
                mx = fmaxf(mx, v);
            }
            #pragma unroll
            for (int m = 1; m < 16; m <<= 1) mx = fmaxf(mx, __shfl_xor(mx, m, 16));
            float sum = 0.f;
            #pragma unroll
            for (int fn = 0; fn < 8; fn++) { vals[fn] = expf(vals[fn] - mx); sum += vals[fn]; }
            #pragma unroll
            for (int m = 1; m < 16; m <<= 1) sum += __shfl_xor(sum, m, 16);
            float inv = 1.f / sum;
            #pragma unroll
            for (int fn = 0; fn < 8; fn++)
                p_s[i * 136 + fn * 16 + li] = f2bf(vals[fn] * inv);
        }
    }
    __syncthreads();

    // PV: out[32 rows x 32 d] per wave
    f32x4 o[2][2];
    #pragma unroll
    for (int i = 0; i < 2; i++)
        #pragma unroll
        for (int j = 0; j < 2; j++) o[i][j] = (f32x4){0.f, 0.f, 0.f, 0.f};
    #pragma unroll
    for (int ks = 0; ks < 4; ks++) {
        bf16x8 pa[2];
        #pragma unroll
        for (int fm = 0; fm < 2; fm++)
            pa[fm] = *(const bf16x8*)&p_s[(wid * 32 + fm * 16 + li) * 136 + ks * 32 + g * 8];
        #pragma unroll
        for (int fn = 0; fn < 2; fn++) {
            bf16x8 vb = *(const bf16x8*)&vt_s[(fn * 16 + li) * 136 + ks * 32 + g * 8];
            o[0][fn] = __builtin_amdgcn_mfma_f32_16x16x32_bf16(pa[0], vb, o[0][fn], 0, 0, 0);
            o[1][fn] = __builtin_amdgcn_mfma_f32_16x16x32_bf16(pa[1], vb, o[1][fn], 0, 0, 0);
        }
    }

    unsigned short* op = attnout + (long)w * 128 * 192 + h * 32;
    #pragma unroll
    for (int fm = 0; fm < 2; fm++) {
        #pragma unroll
        for (int fn = 0; fn < 2; fn++) {
            #pragma unroll
            for (int r = 0; r < 4; r++) {
                int n = wid * 32 + fm * 16 + g * 4 + r;
                op[(long)n * 192 + fn * 16 + li] = f2bf(o[fm][fn][r]);
            }
        }
    }
}

// ---------------- host ----------------
extern "C" void kernel_launch(void* const* d_in, const int* in_sizes, int n_in,
                              void* d_out, int out_size, void* d_ws, size_t ws_size,
                              hipStream_t stream) {
    const float* x   = (const float*)d_in[0];
    const float* g1  = (const float*)d_in[1];
    const float* b1  = (const float*)d_in[2];
    const float* Wq  = (const float*)d_in[3];
    const float* Wkv = (const float*)d_in[4];
    const float* rpb = (const float*)d_in[5];
    const float* Wp  = (const float*)d_in[6];
    const float* bp  = (const float*)d_in[7];
    const float* g2  = (const float*)d_in[8];
    const float* b2  = (const float*)d_in[9];
    const float* Wf1 = (const float*)d_in[10];
    const float* bf1 = (const float*)d_in[11];
    const float* Wf2 = (const float*)d_in[12];
    const float* bf2 = (const float*)d_in[13];
    float* out = (float*)d_out;
    char* ws = (char*)d_ws;

    unsigned short* wcvt = (unsigned short*)ws;
    float* biasT         = (float*)(ws + 917504);
    unsigned short* xw   = (unsigned short*)(ws + 2097152);
    unsigned short* qkvb = (unsigned short*)(ws + 27262976);
    unsigned short* attb = xw;                                    // reuse after QKV
    float* x1            = (float*)(ws + 27262976);               // reuse qkv region
    unsigned short* xn2  = (unsigned short*)(ws + 27262976 + 50331648);
    unsigned short* hbuf = (unsigned short*)(ws + 102760448);

    const unsigned short* wqkv = wcvt;
    const unsigned short* wp_  = wcvt + 110592;
    const unsigned short* wf1_ = wcvt + 147456;
    const unsigned short* wf2_ = wcvt + 294912;

    k_cvt<<<1728, 256, 0, stream>>>(Wq, Wkv, Wp, Wf1, Wf2, wcvt);
    k_bias<<<384, 256, 0, stream>>>(rpb, biasT);
    k_ln<1><<<16384, 256, 0, stream>>>(x, g1, b1, xw);
    k_gemm<0><<<dim3(512, 9), 256, 0, stream>>>(xw, wqkv, 192, nullptr, nullptr, nullptr, qkvb, 0);
    k_attn<<<dim3(512, 6), 256, 0, stream>>>(qkvb, biasT, attb);
    k_gemm<1><<<dim3(512, 3), 256, 0, stream>>>(attb, wp_, 192, bp, x, x1, nullptr, 0);
    k_ln<0><<<16384, 256, 0, stream>>>(x1, g2, b2, xn2);

    long avail = (long)ws_size - 102760448L;
    int rpc = 65536;
    while ((long)rpc * 1536L > avail && rpc > 2048) rpc >>= 1;
    for (int r0 = 0; r0 < 65536; r0 += rpc) {
        k_gemm<2><<<dim3(rpc / 128, 12), 256, 0, stream>>>(xn2 + (long)r0 * 192, wf1_, 192, bf1,
                                                           nullptr, nullptr, hbuf, 0);
        k_gemm<3><<<dim3(rpc / 128, 3), 256, 0, stream>>>(hbuf, wf2_, 768, bf2, x1, out, nullptr, r0);
    }
}

// Round 3
// 258.666 us; speedup vs baseline: 1.1704x; 1.1704x over previous
//
#include <hip/hip_runtime.h>
#include <cstdint>

#define DEVI static __device__ __forceinline__

typedef __attribute__((ext_vector_type(8))) short bf16x8;
typedef __attribute__((ext_vector_type(4))) float f32x4;
typedef __attribute__((ext_vector_type(8))) unsigned short ush8;

DEVI unsigned short f2bf(float f) {
    unsigned u = __float_as_uint(f);
    u += 0x7fff + ((u >> 16) & 1);
    return (unsigned short)(u >> 16);
}
DEVI float bf2f(unsigned short h) { return __uint_as_float(((unsigned)h) << 16); }

DEVI void gload16(const void* g, void* l) {
    __builtin_amdgcn_global_load_lds((const __attribute__((address_space(1))) void*)g,
                                     (__attribute__((address_space(3))) void*)l, 16, 0, 0);
}

// ---------------- weight conversion: fp32 -> bf16 ----------------
__global__ __launch_bounds__(256) void k_cvt(const float* __restrict__ Wq, const float* __restrict__ Wkv,
                                             const float* __restrict__ Wp, const float* __restrict__ Wf1,
                                             const float* __restrict__ Wf2, unsigned short* __restrict__ dst) {
    int t = blockIdx.x * 256 + threadIdx.x;
    if (t < 110592) {
        float v = (t < 36864) ? Wq[t] * 0.17677669529663687f : Wkv[t - 36864];
        dst[t] = f2bf(v);
    } else if (t < 147456) dst[t] = f2bf(Wp[t - 110592]);
    else if (t < 294912) dst[t] = f2bf(Wf1[t - 147456]);
    else if (t < 442368) dst[t] = f2bf(Wf2[t - 294912]);
}

// ---------------- fused bias+mask table: [6 heads][8 variants][128 i][16 li][8 fn] f32 ----------------
// variant bits: b0 = d-boundary window, b1 = h-boundary, b2 = w-boundary.
__global__ __launch_bounds__(256) void k_bmt(const float* __restrict__ rpb, float* __restrict__ bmt) {
    int t = blockIdx.x * 256 + threadIdx.x;  // 6 * 131072
    int h = t >> 17;
    int r = t & 131071;
    int v = r >> 14;
    int ij = r & 16383;
    int i = ij >> 7, li = (ij >> 3) & 15, fn = ij & 7;
    int j = fn * 16 + li;
    int tdi = i >> 6, thi = (i >> 3) & 7, twi = i & 7;
    int tdj = j >> 6, thj = (j >> 3) & 7, twj = j & 7;
    int idx = ((tdi - tdj + 1) * 15 + (thi - thj + 7)) * 15 + (twi - twj + 7);
    float b = rpb[idx * 6 + h];
    int dwb = v & 1, hwb = (v >> 1) & 1, wwb = (v >> 2) & 1;
    int ri = (dwb ? 1 + tdi : 0) * 9 + (hwb ? (thi < 4 ? 1 : 2) : 0) * 3 + (wwb ? (twi < 4 ? 1 : 2) : 0);
    int rj = (dwb ? 1 + tdj : 0) * 9 + (hwb ? (thj < 4 ? 1 : 2) : 0) * 3 + (wwb ? (twj < 4 ? 1 : 2) : 0);
    if (ri != rj) b -= 100.f;
    bmt[(long)(h * 8 + v) * 16384 + i * 128 + li * 8 + fn] = b;
}

// ---------------- LayerNorm (optionally fused with roll+window gather) ----------------
template <int GATHER>
__global__ __launch_bounds__(256) void k_ln(const float* __restrict__ x, const float* __restrict__ g,
                                            const float* __restrict__ b, unsigned short* __restrict__ outp) {
    int wid = threadIdx.x >> 6, lane = threadIdx.x & 63;
    int t = blockIdx.x * 4 + wid;
    long src;
    if (GATHER) {
        int w = t >> 7, tt = t & 127;
        int bb = w >> 8, rem = w & 255;
        int dw = rem >> 6, hw = (rem >> 3) & 7, ww = rem & 7;
        int td = tt >> 6, th = (tt >> 3) & 7, tw = tt & 7;
        int d = (dw * 2 + td + 1) & 7;
        int hh = (hw * 8 + th + 4) & 63;
        int wo = (ww * 8 + tw + 4) & 63;
        src = (long)((bb * 8 + d) * 64 + hh) * 64 + wo;
    } else src = t;
    const float* xp = x + src * 192;
    float v0 = xp[lane], v1 = xp[lane + 64], v2 = xp[lane + 128];
    float s = v0 + v1 + v2, ss = v0 * v0 + v1 * v1 + v2 * v2;
    #pragma unroll
    for (int m = 32; m; m >>= 1) { s += __shfl_xor(s, m); ss += __shfl_xor(ss, m); }
    float mu = s * (1.f / 192.f);
    float var = ss * (1.f / 192.f) - mu * mu;
    float inv = rsqrtf(var + 1e-5f);
    unsigned short* op = outp + (long)t * 192;
    op[lane]       = f2bf((v0 - mu) * inv * g[lane]       + b[lane]);
    op[lane + 64]  = f2bf((v1 - mu) * inv * g[lane + 64]  + b[lane + 64]);
    op[lane + 128] = f2bf((v2 - mu) * inv * g[lane + 128] + b[lane + 128]);
}

// ---------------- generic bf16 MFMA GEMM: C[M,N] = A[M,K] @ B[N,K]^T ----------------
#define BM 128
#define BN 64

template <int EPI>
__global__ __launch_bounds__(256, 2) void k_gemm(const unsigned short* __restrict__ A,
                                                 const unsigned short* __restrict__ Bw, int K,
                                                 const float* __restrict__ bias,
                                                 const float* __restrict__ addsrc,
                                                 float* __restrict__ outF,
                                                 unsigned short* __restrict__ outU, int row0) {
    __shared__ __align__(16) unsigned short As[BM * 32];
    __shared__ __align__(16) unsigned short Bs[BN * 32];
    int tid = threadIdx.x;
    int wid = tid >> 6, lane = tid & 63;
    int g = lane >> 4, li = lane & 15;
    int m0 = blockIdx.x * BM, n0 = blockIdx.y * BN;
    int wm = wid >> 1, wn = wid & 1;

    f32x4 acc[4][2];
    #pragma unroll
    for (int i = 0; i < 4; i++)
        #pragma unroll
        for (int j = 0; j < 2; j++) acc[i][j] = (f32x4){0.f, 0.f, 0.f, 0.f};

    const unsigned short* ga0 = A + (long)(m0 + (tid >> 2)) * K + (tid & 3) * 8;
    const unsigned short* ga1 = A + (long)(m0 + 64 + (tid >> 2)) * K + (tid & 3) * 8;
    const unsigned short* gb  = Bw + (long)(n0 + (tid >> 2)) * K + (tid & 3) * 8;

    for (int kt = 0; kt < K; kt += 32) {
        gload16(ga0 + kt, As + tid * 8);
        gload16(ga1 + kt, As + (256 + tid) * 8);
        gload16(gb + kt, Bs + tid * 8);
        __syncthreads();
        bf16x8 af[4], bfr[2];
        #pragma unroll
        for (int i = 0; i < 4; i++)
            af[i] = *(const bf16x8*)&As[(wm * 64 + i * 16 + li) * 32 + g * 8];
        #pragma unroll
        for (int j = 0; j < 2; j++)
            bfr[j] = *(const bf16x8*)&Bs[(wn * 32 + j * 16 + li) * 32 + g * 8];
        #pragma unroll
        for (int i = 0; i < 4; i++)
            #pragma unroll
            for (int j = 0; j < 2; j++)
                acc[i][j] = __builtin_amdgcn_mfma_f32_16x16x32_bf16(af[i], bfr[j], acc[i][j], 0, 0, 0);
        __syncthreads();
    }

    #pragma unroll
    for (int i = 0; i < 4; i++) {
        int rowb = m0 + wm * 64 + i * 16 + g * 4;
        #pragma unroll
        for (int j = 0; j < 2; j++) {
            int col = n0 + wn * 32 + j * 16 + li;
            #pragma unroll
            for (int r = 0; r < 4; r++) {
                float v = acc[i][j][r];
                int rr = rowb + r;
                if (EPI == 0) {
                    int sec = col / 192;
                    int cc = col - sec * 192;
                    int h = cc >> 5, d = cc & 31;
                    int w = rr >> 7, n = rr & 127;
                    outU[(((long)sec * 3072 + w * 6 + h) * 128 + n) * 32 + d] = f2bf(v);
                } else if (EPI == 1) {
                    int w = rr >> 7, tt = rr & 127;
                    int bb = w >> 8, rem = w & 255;
                    int dw = rem >> 6, hw = (rem >> 3) & 7, ww = rem & 7;
                    int td = tt >> 6, th = (tt >> 3) & 7, tw = tt & 7;
                    int d = (dw * 2 + td + 1) & 7;
                    int hh = (hw * 8 + th + 4) & 63;
                    int wo = (ww * 8 + tw + 4) & 63;
                    long src = ((long)((bb * 8 + d) * 64 + hh) * 64 + wo) * 192 + col;
                    outF[src] = addsrc[src] + v + bias[col];
                } else if (EPI == 2) {
                    float tt = v + bias[col];
                    float ge = 0.5f * tt * (1.f + erff(tt * 0.70710678118f));
                    outU[(long)rr * 768 + col] = f2bf(ge);
                } else {
                    long idx = (long)(row0 + rr) * 192 + col;
                    outF[idx] = addsrc[idx] + v + bias[col];
                }
            }
        }
    }
}

// ---------------- attention: one block per (window, head) ----------------
__global__ __launch_bounds__(256, 2) void k_attn(const unsigned short* __restrict__ qkv,
                                                 const float* __restrict__ bmt,
                                                 unsigned short* __restrict__ attnout) {
    // LDS: union { q_s[128*36] | k_s[128*36]  (18432B) , p_s[128*132] (33792B) } + vt_s[32*136] (8704B)
    __shared__ __align__(16) char smem[42496];
    unsigned short* q_s  = (unsigned short*)smem;
    unsigned short* k_s  = q_s + 128 * 36;
    unsigned short* p_s  = (unsigned short*)smem;
    unsigned short* vt_s = (unsigned short*)(smem + 33792);

    int w = blockIdx.x, h = blockIdx.y;
    int tid = threadIdx.x, wid = tid >> 6, lane = tid & 63, g = lane >> 4, li = lane & 15;
    int rem = w & 255;
    int dw = rem >> 6, hw = (rem >> 3) & 7, ww = rem & 7;
    int variant = (dw == 3 ? 1 : 0) | (hw == 7 ? 2 : 0) | (ww == 7 ? 4 : 0);
    const float* bm = bmt + (long)(h * 8 + variant) * 16384;

    const unsigned short* qg = qkv + (long)(w * 6 + h) * 4096;
    const unsigned short* kg = qg + (long)3072 * 4096;
    const unsigned short* vg = qg + (long)6144 * 4096;

    #pragma unroll
    for (int c = tid; c < 512; c += 256) {
        int row = c >> 2, sub = c & 3;
        *(uint4*)&q_s[row * 36 + sub * 8] = *(const uint4*)&qg[row * 32 + sub * 8];
        *(uint4*)&k_s[row * 36 + sub * 8] = *(const uint4*)&kg[row * 32 + sub * 8];
    }
    {
        int key = tid >> 1, d0 = (tid & 1) * 16;
        const unsigned short* vp = vg + key * 32 + d0;
        ush8 va = *(const ush8*)vp, vb = *(const ush8*)(vp + 8);
        #pragma unroll
        for (int dd = 0; dd < 8; dd++) vt_s[(d0 + dd) * 136 + key] = va[dd];
        #pragma unroll
        for (int dd = 0; dd < 8; dd++) vt_s[(d0 + 8 + dd) * 136 + key] = vb[dd];
    }
    __syncthreads();

    // QK^T: wave wid owns query rows wid*32 .. wid*32+31
    f32x4 s[2][8];
    #pragma unroll
    for (int i = 0; i < 2; i++)
        #pragma unroll
        for (int j = 0; j < 8; j++) s[i][j] = (f32x4){0.f, 0.f, 0.f, 0.f};
    bf16x8 qa[2];
    #pragma unroll
    for (int fm = 0; fm < 2; fm++)
        qa[fm] = *(const bf16x8*)&q_s[(wid * 32 + fm * 16 + li) * 36 + g * 8];
    #pragma unroll
    for (int fn = 0; fn < 8; fn++) {
        bf16x8 kb = *(const bf16x8*)&k_s[(fn * 16 + li) * 36 + g * 8];
        s[0][fn] = __builtin_amdgcn_mfma_f32_16x16x32_bf16(qa[0], kb, s[0][fn], 0, 0, 0);
        s[1][fn] = __builtin_amdgcn_mfma_f32_16x16x32_bf16(qa[1], kb, s[1][fn], 0, 0, 0);
    }
    __syncthreads();   // q_s/k_s dead after this; p_s overlays them

    // bias(+mask) + softmax + write P (bf16) to LDS
    #pragma unroll
    for (int fm = 0; fm < 2; fm++) {
        #pragma unroll
        for (int r = 0; r < 4; r++) {
            int i = wid * 32 + fm * 16 + g * 4 + r;
            const float4 b0 = *(const float4*)&bm[i * 128 + li * 8];
            const float4 b1 = *(const float4*)&bm[i * 128 + li * 8 + 4];
            float vals[8];
            vals[0] = s[fm][0][r] + b0.x; vals[1] = s[fm][1][r] + b0.y;
            vals[2] = s[fm][2][r] + b0.z; vals[3] = s[fm][3][r] + b0.w;
            vals[4] = s[fm][4][r] + b1.x; vals[5] = s[fm][5][r] + b1.y;
            vals[6] = s[fm][6][r] + b1.z; vals[7] = s[fm][7][r] + b1.w;
            float mx = fmaxf(fmaxf(fmaxf(vals[0], vals[1]), fmaxf(vals[2], vals[3])),
                             fmaxf(fmaxf(vals[4], vals[5]), fmaxf(vals[6], vals[7])));
            #pragma unroll
            for (int m = 1; m < 16; m <<= 1) mx = fmaxf(mx, __shfl_xor(mx, m, 16));
            float sum = 0.f;
            #pragma unroll
            for (int fn = 0; fn < 8; fn++) { vals[fn] = __expf(vals[fn] - mx); sum += vals[fn]; }
            #pragma unroll
            for (int m = 1; m < 16; m <<= 1) sum += __shfl_xor(sum, m, 16);
            float inv = 1.f / sum;
            #pragma unroll
            for (int fn = 0; fn < 8; fn++)
                p_s[i * 132 + fn * 16 + li] = f2bf(vals[fn] * inv);
        }
    }

    // PV: out[32 rows x 32 d] per wave (reads only this wave's own p rows)
    f32x4 o[2][2];
    #pragma unroll
    for (int i = 0; i < 2; i++)
        #pragma unroll
        for (int j = 0; j < 2; j++) o[i][j] = (f32x4){0.f, 0.f, 0.f, 0.f};
    #pragma unroll
    for (int ks = 0; ks < 4; ks++) {
        bf16x8 pa[2];
        #pragma unroll
        for (int fm = 0; fm < 2; fm++)
            pa[fm] = *(const bf16x8*)&p_s[(wid * 32 + fm * 16 + li) * 132 + ks * 32 + g * 8];
        #pragma unroll
        for (int fn = 0; fn < 2; fn++) {
            bf16x8 vb = *(const bf16x8*)&vt_s[(fn * 16 + li) * 136 + ks * 32 + g * 8];
            o[0][fn] = __builtin_amdgcn_mfma_f32_16x16x32_bf16(pa[0], vb, o[0][fn], 0, 0, 0);
            o[1][fn] = __builtin_amdgcn_mfma_f32_16x16x32_bf16(pa[1], vb, o[1][fn], 0, 0, 0);
        }
    }

    unsigned short* op = attnout + (long)w * 128 * 192 + h * 32;
    #pragma unroll
    for (int fm = 0; fm < 2; fm++) {
        #pragma unroll
        for (int fn = 0; fn < 2; fn++) {
            #pragma unroll
            for (int r = 0; r < 4; r++) {
                int n = wid * 32 + fm * 16 + g * 4 + r;
                op[(long)n * 192 + fn * 16 + li] = f2bf(o[fm][fn][r]);
            }
        }
    }
}

// ---------------- host ----------------
extern "C" void kernel_launch(void* const* d_in, const int* in_sizes, int n_in,
                              void* d_out, int out_size, void* d_ws, size_t ws_size,
                              hipStream_t stream) {
    const float* x   = (const float*)d_in[0];
    const float* g1  = (const float*)d_in[1];
    const float* b1  = (const float*)d_in[2];
    const float* Wq  = (const float*)d_in[3];
    const float* Wkv = (const float*)d_in[4];
    const float* rpb = (const float*)d_in[5];
    const float* Wp  = (const float*)d_in[6];
    const float* bp  = (const float*)d_in[7];
    const float* g2  = (const float*)d_in[8];
    const float* b2  = (const float*)d_in[9];
    const float* Wf1 = (const float*)d_in[10];
    const float* bf1 = (const float*)d_in[11];
    const float* Wf2 = (const float*)d_in[12];
    const float* bf2 = (const float*)d_in[13];
    float* out = (float*)d_out;
    char* ws = (char*)d_ws;

    unsigned short* wcvt = (unsigned short*)ws;               // 884736 B
    float* bmt           = (float*)(ws + 917504);             // 3145728 B -> ends 4063232
    unsigned short* xw   = (unsigned short*)(ws + 4194304);   // 25165824 B -> ends 29360128
    unsigned short* qkvb = (unsigned short*)(ws + 29360128);  // 75497472 B -> ends 104857600
    unsigned short* attb = xw;                                // reuse after QKV consumed
    float* x1            = (float*)(ws + 29360128);           // 50331648 B (reuses qkv region)
    unsigned short* xn2  = (unsigned short*)(ws + 79691776);  // 25165824 B -> ends 104857600
    unsigned short* hbuf = (unsigned short*)(ws + 104857600); // up to 100663296 B

    const unsigned short* wqkv = wcvt;
    const unsigned short* wp_  = wcvt + 110592;
    const unsigned short* wf1_ = wcvt + 147456;
    const unsigned short* wf2_ = wcvt + 294912;

    k_cvt<<<1728, 256, 0, stream>>>(Wq, Wkv, Wp, Wf1, Wf2, wcvt);
    k_bmt<<<3072, 256, 0, stream>>>(rpb, bmt);
    k_ln<1><<<16384, 256, 0, stream>>>(x, g1, b1, xw);
    k_gemm<0><<<dim3(512, 9), 256, 0, stream>>>(xw, wqkv, 192, nullptr, nullptr, nullptr, qkvb, 0);
    k_attn<<<dim3(512, 6), 256, 0, stream>>>(qkvb, bmt, attb);
    k_gemm<1><<<dim3(512, 3), 256, 0, stream>>>(attb, wp_, 192, bp, x, x1, nullptr, 0);
    k_ln<0><<<16384, 256, 0, stream>>>(x1, g2, b2, xn2);

    long avail = (long)ws_size - 104857600L;
    int rpc = 65536;
    while ((long)rpc * 1536L > avail && rpc > 2048) rpc >>= 1;
    for (int r0 = 0; r0 < 65536; r0 += rpc) {
        k_gemm<2><<<dim3(rpc / 128, 12), 256, 0, stream>>>(xn2 + (long)r0 * 192, wf1_, 192, bf1,
                                                           nullptr, nullptr, hbuf, 0);
        k_gemm<3><<<dim3(rpc / 128, 3), 256, 0, stream>>>(hbuf, wf2_, 768, bf2, x1, out, nullptr, r0);
    }
}

// Round 4
// 251.472 us; speedup vs baseline: 1.2038x; 1.0286x over previous
//
#include <hip/hip_runtime.h>
#include <cstdint>

#define DEVI static __device__ __forceinline__

typedef __attribute__((ext_vector_type(8))) short bf16x8;
typedef __attribute__((ext_vector_type(4))) float f32x4;
typedef __attribute__((ext_vector_type(8))) unsigned short ush8;

DEVI unsigned short f2bf(float f) {
    unsigned u = __float_as_uint(f);
    u += 0x7fff + ((u >> 16) & 1);
    return (unsigned short)(u >> 16);
}
DEVI float bf2f(unsigned short h) { return __uint_as_float(((unsigned)h) << 16); }

DEVI void gload16(const void* g, void* l) {
    __builtin_amdgcn_global_load_lds((const __attribute__((address_space(1))) void*)g,
                                     (__attribute__((address_space(3))) void*)l, 16, 0, 0);
}

DEVI float fast_gelu(float x) {
    // tanh-approx GELU: x * sigmoid(1.5957691*(x + 0.044715 x^3)); |err vs erf-gelu| <~3e-3
    float z = 1.5957691216057308f * (x + 0.044715f * x * x * x);
    return x - x / (__expf(z) + 1.f);
}

// ---------------- weight conversion: fp32 -> bf16 ----------------
__global__ __launch_bounds__(256) void k_cvt(const float* __restrict__ Wq, const float* __restrict__ Wkv,
                                             const float* __restrict__ Wp, const float* __restrict__ Wf1,
                                             const float* __restrict__ Wf2, unsigned short* __restrict__ dst) {
    int t = blockIdx.x * 256 + threadIdx.x;
    if (t < 110592) {
        float v = (t < 36864) ? Wq[t] * 0.17677669529663687f : Wkv[t - 36864];
        dst[t] = f2bf(v);
    } else if (t < 147456) dst[t] = f2bf(Wp[t - 110592]);
    else if (t < 294912) dst[t] = f2bf(Wf1[t - 147456]);
    else if (t < 442368) dst[t] = f2bf(Wf2[t - 294912]);
}

// ---------------- fused bias+mask table: [6 heads][8 variants][128 i][16 li][8 fn] f32 ----------------
__global__ __launch_bounds__(256) void k_bmt(const float* __restrict__ rpb, float* __restrict__ bmt) {
    int t = blockIdx.x * 256 + threadIdx.x;  // 6 * 131072
    int h = t >> 17;
    int r = t & 131071;
    int v = r >> 14;
    int ij = r & 16383;
    int i = ij >> 7, li = (ij >> 3) & 15, fn = ij & 7;
    int j = fn * 16 + li;
    int tdi = i >> 6, thi = (i >> 3) & 7, twi = i & 7;
    int tdj = j >> 6, thj = (j >> 3) & 7, twj = j & 7;
    int idx = ((tdi - tdj + 1) * 15 + (thi - thj + 7)) * 15 + (twi - twj + 7);
    float b = rpb[idx * 6 + h];
    int dwb = v & 1, hwb = (v >> 1) & 1, wwb = (v >> 2) & 1;
    int ri = (dwb ? 1 + tdi : 0) * 9 + (hwb ? (thi < 4 ? 1 : 2) : 0) * 3 + (wwb ? (twi < 4 ? 1 : 2) : 0);
    int rj = (dwb ? 1 + tdj : 0) * 9 + (hwb ? (thj < 4 ? 1 : 2) : 0) * 3 + (wwb ? (twj < 4 ? 1 : 2) : 0);
    if (ri != rj) b -= 100.f;
    bmt[(long)(h * 8 + v) * 16384 + i * 128 + li * 8 + fn] = b;
}

// ---------------- LayerNorm (optionally fused with roll+window gather) ----------------
template <int GATHER>
__global__ __launch_bounds__(256) void k_ln(const float* __restrict__ x, const float* __restrict__ g,
                                            const float* __restrict__ b, unsigned short* __restrict__ outp) {
    int wid = threadIdx.x >> 6, lane = threadIdx.x & 63;
    int t = blockIdx.x * 4 + wid;
    long src;
    if (GATHER) {
        int w = t >> 7, tt = t & 127;
        int bb = w >> 8, rem = w & 255;
        int dw = rem >> 6, hw = (rem >> 3) & 7, ww = rem & 7;
        int td = tt >> 6, th = (tt >> 3) & 7, tw = tt & 7;
        int d = (dw * 2 + td + 1) & 7;
        int hh = (hw * 8 + th + 4) & 63;
        int wo = (ww * 8 + tw + 4) & 63;
        src = (long)((bb * 8 + d) * 64 + hh) * 64 + wo;
    } else src = t;
    const float* xp = x + src * 192;
    float v0 = xp[lane], v1 = xp[lane + 64], v2 = xp[lane + 128];
    float s = v0 + v1 + v2, ss = v0 * v0 + v1 * v1 + v2 * v2;
    #pragma unroll
    for (int m = 32; m; m >>= 1) { s += __shfl_xor(s, m); ss += __shfl_xor(ss, m); }
    float mu = s * (1.f / 192.f);
    float var = ss * (1.f / 192.f) - mu * mu;
    float inv = rsqrtf(var + 1e-5f);
    unsigned short* op = outp + (long)t * 192;
    op[lane]       = f2bf((v0 - mu) * inv * g[lane]       + b[lane]);
    op[lane + 64]  = f2bf((v1 - mu) * inv * g[lane + 64]  + b[lane + 64]);
    op[lane + 128] = f2bf((v2 - mu) * inv * g[lane + 128] + b[lane + 128]);
}

// ---------------- bf16 MFMA GEMM: C[M,N] = A[M,K] @ B[N,K]^T ----------------
// 256x64 tile, 4 waves stacked in M (wave tile 64x64 = 4x4 frags of 16x16), BK=32.
// Double-buffered LDS, 2-phase schedule (stage t+1 || compute t, one barrier/step).
// LDS layout XOR-swizzled: col-group g of row stored at slot g ^ ((row>>1)&3)
// (applied on the global source address since global_load_lds dest is linear).
// EPI: 0=QKV scatter, 1=proj + window-reverse + residual (f32), 2=bias+GELU (bf16), 3=bias+residual (f32)

template <int EPI>
__global__ __launch_bounds__(256, 2) void k_gemm(const unsigned short* __restrict__ A,
                                                 const unsigned short* __restrict__ Bw, int K,
                                                 const float* __restrict__ bias,
                                                 const float* __restrict__ addsrc,
                                                 float* __restrict__ outF,
                                                 unsigned short* __restrict__ outU, int row0) {
    __shared__ __align__(16) unsigned short As[2][256 * 32];
    __shared__ __align__(16) unsigned short Bs[2][64 * 32];
    int tid = threadIdx.x;
    int wid = tid >> 6, lane = tid & 63;
    int g = lane >> 4, li = lane & 15;
    int m0 = blockIdx.x * 256, n0 = blockIdx.y * 64;

    f32x4 acc[4][4];
    #pragma unroll
    for (int i = 0; i < 4; i++)
        #pragma unroll
        for (int j = 0; j < 4; j++) acc[i][j] = (f32x4){0.f, 0.f, 0.f, 0.f};

    // staging pointers: thread t loads 16B of row (c*64 + t>>2), col-group g = (t&3) ^ ((t>>3)&3)
    int sg = ((tid & 3) ^ ((tid >> 3) & 3)) * 8;
    const unsigned short* pa = A + (long)(m0 + (tid >> 2)) * K + sg;
    const unsigned short* pb = Bw + (long)(n0 + (tid >> 2)) * K + sg;

#define STAGE(buf, kt) do { \
    _Pragma("unroll") \
    for (int c = 0; c < 4; c++) \
        gload16(pa + (long)(c * 64) * K + (kt), &As[buf][c * 2048 + tid * 8]); \
    gload16(pb + (kt), &Bs[buf][tid * 8]); \
} while (0)

    STAGE(0, 0);
    __syncthreads();

    int nt = K >> 5;
    int cur = 0;
    int swz8 = ((li >> 1) & 3);          // read-side swizzle base
    int acol = ((g ^ swz8)) * 8;
    for (int t = 0; t < nt; t++) {
        if (t + 1 < nt) STAGE(cur ^ 1, (t + 1) << 5);
        const unsigned short* ab = &As[cur][(wid * 64 + li) * 32 + acol];
        const unsigned short* bb = &Bs[cur][li * 32 + acol];
        bf16x8 af[4], bfr[4];
        #pragma unroll
        for (int i = 0; i < 4; i++) af[i] = *(const bf16x8*)(ab + i * 512);
        #pragma unroll
        for (int j = 0; j < 4; j++) bfr[j] = *(const bf16x8*)(bb + j * 512);
        #pragma unroll
        for (int i = 0; i < 4; i++)
            #pragma unroll
            for (int j = 0; j < 4; j++)
                acc[i][j] = __builtin_amdgcn_mfma_f32_16x16x32_bf16(af[i], bfr[j], acc[i][j], 0, 0, 0);
        if (t + 1 < nt) {
            __syncthreads();
            cur ^= 1;
        }
    }
#undef STAGE

    #pragma unroll
    for (int i = 0; i < 4; i++) {
        int rowb = m0 + wid * 64 + i * 16 + g * 4;
        #pragma unroll
        for (int j = 0; j < 4; j++) {
            int col = n0 + j * 16 + li;
            #pragma unroll
            for (int r = 0; r < 4; r++) {
                float v = acc[i][j][r];
                int rr = rowb + r;
                if (EPI == 0) {
                    int sec = col / 192;
                    int cc = col - sec * 192;
                    int h = cc >> 5, d = cc & 31;
                    int w = rr >> 7, n = rr & 127;
                    outU[(((long)sec * 3072 + w * 6 + h) * 128 + n) * 32 + d] = f2bf(v);
                } else if (EPI == 1) {
                    int w = rr >> 7, tt = rr & 127;
                    int bb2 = w >> 8, rem = w & 255;
                    int dw = rem >> 6, hw = (rem >> 3) & 7, ww = rem & 7;
                    int td = tt >> 6, th = (tt >> 3) & 7, tw = tt & 7;
                    int d = (dw * 2 + td + 1) & 7;
                    int hh = (hw * 8 + th + 4) & 63;
                    int wo = (ww * 8 + tw + 4) & 63;
                    long src = ((long)((bb2 * 8 + d) * 64 + hh) * 64 + wo) * 192 + col;
                    outF[src] = addsrc[src] + v + bias[col];
                } else if (EPI == 2) {
                    outU[(long)rr * 768 + col] = f2bf(fast_gelu(v + bias[col]));
                } else {
                    long idx = (long)(row0 + rr) * 192 + col;
                    outF[idx] = addsrc[idx] + v + bias[col];
                }
            }
        }
    }
}

// ---------------- attention: one block per (window, head) ----------------
__global__ __launch_bounds__(256, 2) void k_attn(const unsigned short* __restrict__ qkv,
                                                 const float* __restrict__ bmt,
                                                 unsigned short* __restrict__ attnout) {
    // LDS: union { q_s[128*36] | k_s[128*36]  (18432B each) , p_s[128*132] (33792B) } + vt_s[32*136] (8704B)
    __shared__ __align__(16) char smem[42496];
    unsigned short* q_s  = (unsigned short*)smem;
    unsigned short* k_s  = q_s + 128 * 36;
    unsigned short* p_s  = (unsigned short*)smem;
    unsigned short* vt_s = (unsigned short*)(smem + 33792);

    int w = blockIdx.x, h = blockIdx.y;
    int tid = threadIdx.x, wid = tid >> 6, lane = tid & 63, g = lane >> 4, li = lane & 15;
    int rem = w & 255;
    int dw = rem >> 6, hw = (rem >> 3) & 7, ww = rem & 7;
    int variant = (dw == 3 ? 1 : 0) | (hw == 7 ? 2 : 0) | (ww == 7 ? 4 : 0);
    const float* bm = bmt + (long)(h * 8 + variant) * 16384;

    const unsigned short* qg = qkv + (long)(w * 6 + h) * 4096;
    const unsigned short* kg = qg + (long)3072 * 4096;
    const unsigned short* vg = qg + (long)6144 * 4096;

    #pragma unroll
    for (int c = tid; c < 512; c += 256) {
        int row = c >> 2, sub = c & 3;
        *(uint4*)&q_s[row * 36 + sub * 8] = *(const uint4*)&qg[row * 32 + sub * 8];
        *(uint4*)&k_s[row * 36 + sub * 8] = *(const uint4*)&kg[row * 32 + sub * 8];
    }
    {
        int key = tid >> 1, d0 = (tid & 1) * 16;
        const unsigned short* vp = vg + key * 32 + d0;
        ush8 va = *(const ush8*)vp, vb = *(const ush8*)(vp + 8);
        #pragma unroll
        for (int dd = 0; dd < 8; dd++) vt_s[(d0 + dd) * 136 + key] = va[dd];
        #pragma unroll
        for (int dd = 0; dd < 8; dd++) vt_s[(d0 + 8 + dd) * 136 + key] = vb[dd];
    }
    __syncthreads();

    // QK^T: wave wid owns query rows wid*32 .. wid*32+31
    f32x4 s[2][8];
    #pragma unroll
    for (int i = 0; i < 2; i++)
        #pragma unroll
        for (int j = 0; j < 8; j++) s[i][j] = (f32x4){0.f, 0.f, 0.f, 0.f};
    bf16x8 qa[2];
    #pragma unroll
    for (int fm = 0; fm < 2; fm++)
        qa[fm] = *(const bf16x8*)&q_s[(wid * 32 + fm * 16 + li) * 36 + g * 8];
    #pragma unroll
    for (int fn = 0; fn < 8; fn++) {
        bf16x8 kb = *(const bf16x8*)&k_s[(fn * 16 + li) * 36 + g * 8];
        s[0][fn] = __builtin_amdgcn_mfma_f32_16x16x32_bf16(qa[0], kb, s[0][fn], 0, 0, 0);
        s[1][fn] = __builtin_amdgcn_mfma_f32_16x16x32_bf16(qa[1], kb, s[1][fn], 0, 0, 0);
    }
    __syncthreads();   // q_s/k_s dead after this; p_s overlays them

    // bias(+mask) + softmax + write P (bf16) to LDS
    #pragma unroll
    for (int fm = 0; fm < 2; fm++) {
        #pragma unroll
        for (int r = 0; r < 4; r++) {
            int i = wid * 32 + fm * 16 + g * 4 + r;
            const float4 b0 = *(const float4*)&bm[i * 128 + li * 8];
            const float4 b1 = *(const float4*)&bm[i * 128 + li * 8 + 4];
            float vals[8];
            vals[0] = s[fm][0][r] + b0.x; vals[1] = s[fm][1][r] + b0.y;
            vals[2] = s[fm][2][r] + b0.z; vals[3] = s[fm][3][r] + b0.w;
            vals[4] = s[fm][4][r] + b1.x; vals[5] = s[fm][5][r] + b1.y;
            vals[6] = s[fm][6][r] + b1.z; vals[7] = s[fm][7][r] + b1.w;
            float mx = fmaxf(fmaxf(fmaxf(vals[0], vals[1]), fmaxf(vals[2], vals[3])),
                             fmaxf(fmaxf(vals[4], vals[5]), fmaxf(vals[6], vals[7])));
            #pragma unroll
            for (int m = 1; m < 16; m <<= 1) mx = fmaxf(mx, __shfl_xor(mx, m, 16));
            float sum = 0.f;
            #pragma unroll
            for (int fn = 0; fn < 8; fn++) { vals[fn] = __expf(vals[fn] - mx); sum += vals[fn]; }
            #pragma unroll
            for (int m = 1; m < 16; m <<= 1) sum += __shfl_xor(sum, m, 16);
            float inv = 1.f / sum;
            #pragma unroll
            for (int fn = 0; fn < 8; fn++)
                p_s[i * 132 + fn * 16 + li] = f2bf(vals[fn] * inv);
        }
    }

    // PV: out[32 rows x 32 d] per wave (reads only this wave's own p rows)
    f32x4 o[2][2];
    #pragma unroll
    for (int i = 0; i < 2; i++)
        #pragma unroll
        for (int j = 0; j < 2; j++) o[i][j] = (f32x4){0.f, 0.f, 0.f, 0.f};
    #pragma unroll
    for (int ks = 0; ks < 4; ks++) {
        bf16x8 pa[2];
        #pragma unroll
        for (int fm = 0; fm < 2; fm++)
            pa[fm] = *(const bf16x8*)&p_s[(wid * 32 + fm * 16 + li) * 132 + ks * 32 + g * 8];
        #pragma unroll
        for (int fn = 0; fn < 2; fn++) {
            bf16x8 vb = *(const bf16x8*)&vt_s[(fn * 16 + li) * 136 + ks * 32 + g * 8];
            o[0][fn] = __builtin_amdgcn_mfma_f32_16x16x32_bf16(pa[0], vb, o[0][fn], 0, 0, 0);
            o[1][fn] = __builtin_amdgcn_mfma_f32_16x16x32_bf16(pa[1], vb, o[1][fn], 0, 0, 0);
        }
    }

    unsigned short* op = attnout + (long)w * 128 * 192 + h * 32;
    #pragma unroll
    for (int fm = 0; fm < 2; fm++) {
        #pragma unroll
        for (int fn = 0; fn < 2; fn++) {
            #pragma unroll
            for (int r = 0; r < 4; r++) {
                int n = wid * 32 + fm * 16 + g * 4 + r;
                op[(long)n * 192 + fn * 16 + li] = f2bf(o[fm][fn][r]);
            }
        }
    }
}

// ---------------- host ----------------
extern "C" void kernel_launch(void* const* d_in, const int* in_sizes, int n_in,
                              void* d_out, int out_size, void* d_ws, size_t ws_size,
                              hipStream_t stream) {
    const float* x   = (const float*)d_in[0];
    const float* g1  = (const float*)d_in[1];
    const float* b1  = (const float*)d_in[2];
    const float* Wq  = (const float*)d_in[3];
    const float* Wkv = (const float*)d_in[4];
    const float* rpb = (const float*)d_in[5];
    const float* Wp  = (const float*)d_in[6];
    const float* bp  = (const float*)d_in[7];
    const float* g2  = (const float*)d_in[8];
    const float* b2  = (const float*)d_in[9];
    const float* Wf1 = (const float*)d_in[10];
    const float* bf1 = (const float*)d_in[11];
    const float* Wf2 = (const float*)d_in[12];
    const float* bf2 = (const float*)d_in[13];
    float* out = (float*)d_out;
    char* ws = (char*)d_ws;

    unsigned short* wcvt = (unsigned short*)ws;               // 884736 B
    float* bmt           = (float*)(ws + 917504);             // 3145728 B -> ends 4063232
    unsigned short* xw   = (unsigned short*)(ws + 4194304);   // 25165824 B -> ends 29360128
    unsigned short* qkvb = (unsigned short*)(ws + 29360128);  // 75497472 B -> ends 104857600
    unsigned short* attb = xw;                                // reuse after QKV consumed
    float* x1            = (float*)(ws + 29360128);           // 50331648 B (reuses qkv region)
    unsigned short* xn2  = (unsigned short*)(ws + 79691776);  // 25165824 B -> ends 104857600
    unsigned short* hbuf = (unsigned short*)(ws + 104857600); // up to 100663296 B

    const unsigned short* wqkv = wcvt;
    const unsigned short* wp_  = wcvt + 110592;
    const unsigned short* wf1_ = wcvt + 147456;
    const unsigned short* wf2_ = wcvt + 294912;

    k_cvt<<<1728, 256, 0, stream>>>(Wq, Wkv, Wp, Wf1, Wf2, wcvt);
    k_bmt<<<3072, 256, 0, stream>>>(rpb, bmt);
    k_ln<1><<<16384, 256, 0, stream>>>(x, g1, b1, xw);
    k_gemm<0><<<dim3(256, 9), 256, 0, stream>>>(xw, wqkv, 192, nullptr, nullptr, nullptr, qkvb, 0);
    k_attn<<<dim3(512, 6), 256, 0, stream>>>(qkvb, bmt, attb);
    k_gemm<1><<<dim3(256, 3), 256, 0, stream>>>(attb, wp_, 192, bp, x, x1, nullptr, 0);
    k_ln<0><<<16384, 256, 0, stream>>>(x1, g2, b2, xn2);

    long avail = (long)ws_size - 104857600L;
    int rpc = 65536;
    while ((long)rpc * 1536L > avail && rpc > 2048) rpc >>= 1;
    for (int r0 = 0; r0 < 65536; r0 += rpc) {
        k_gemm<2><<<dim3(rpc / 256, 12), 256, 0, stream>>>(xn2 + (long)r0 * 192, wf1_, 192, bf1,
                                                           nullptr, nullptr, hbuf, 0);
        k_gemm<3><<<dim3(rpc / 256, 3), 256, 0, stream>>>(hbuf, wf2_, 768, bf2, x1, out, nullptr, r0);
    }
}